// Round 2
// baseline (694.656 us; speedup 1.0000x reference)
//
#include <hip/hip_runtime.h>
#include <cstdint>
#include <cstddef>

typedef _Float16 f16;
typedef f16 f16x4 __attribute__((ext_vector_type(4)));
typedef f16 f16x8 __attribute__((ext_vector_type(8)));
typedef float f32x4 __attribute__((ext_vector_type(4)));

// ---------------- f32 -> f16 convert (4 elems/thread) ----------------
__global__ __launch_bounds__(256) void k_cvt(const float* __restrict__ in,
                                             f16* __restrict__ out, int n4) {
  int idx = blockIdx.x * 256 + threadIdx.x;
  if (idx < n4) {
    float4 v = ((const float4*)in)[idx];
    f16x4 o;
    o.x = (f16)v.x; o.y = (f16)v.y; o.z = (f16)v.z; o.w = (f16)v.w;
    ((f16x4*)out)[idx] = o;
  }
}

// ------------- transpose f32[K][N] -> f16[N][K], 64x64 tiles -------------
__global__ __launch_bounds__(256) void k_transpose(const float* __restrict__ in,
                                                   f16* __restrict__ out,
                                                   int K, int N) {
  __shared__ float tile[64][65];
  const int t = threadIdx.x, x = t & 63, y0 = t >> 6;
  const int bx = blockIdx.x, by = blockIdx.y;  // bx tiles N, by tiles K
#pragma unroll
  for (int r = 0; r < 16; ++r) {
    int y = y0 + r * 4;
    tile[y][x] = in[(size_t)(by * 64 + y) * N + bx * 64 + x];
  }
  __syncthreads();
#pragma unroll
  for (int r = 0; r < 16; ++r) {
    int y = y0 + r * 4;
    out[(size_t)(bx * 64 + y) * K + by * 64 + x] = (f16)tile[x][y];
  }
}

// ------------- GEMM: C[M][N] = A[M][K] * Bt[N][K]^T  (f16 in, fp32 acc) ----
// 128x128 tile, BK=64, 256 threads (4 waves, 2x2), 4x4 16x16x32 MFMAs/wave.
template <int F32OUT>
__global__ __launch_bounds__(256) void k_gemm_bt(const f16* __restrict__ A,
                                                 const f16* __restrict__ Bt,
                                                 void* __restrict__ Cout,
                                                 int M, int N, int K) {
  constexpr int LDK = 72;  // 64 + 8 pad (keeps 16B alignment, breaks pow2 stride)
  __shared__ __align__(16) f16 As[128 * LDK];
  __shared__ __align__(16) f16 Bs[128 * LDK];
  const int t = threadIdx.x;
  const int m0 = blockIdx.x * 128, n0 = blockIdx.y * 128;
  const int w = t >> 6, l = t & 63, sl = l & 15, quad = l >> 4;
  const int wm = (w & 1) * 64, wn = (w >> 1) * 64;
  f32x4 acc[4][4] = {};
  const int nk = K >> 6;
  for (int kt = 0; kt < nk; ++kt) {
    __syncthreads();
    // stage 128 rows x 64 f16 (=8 x 16B chunks/row) for A and Bt:
    // 1024 chunks each, 4 per thread per matrix. 8 threads cover one row.
#pragma unroll
    for (int c = 0; c < 4; ++c) {
      int cid = t + c * 256;      // 0..1023
      int row = cid >> 3;         // 0..127
      int kc = (cid & 7) * 8;     // 0,8,...,56 (f16 units)
      *(uint4*)(As + row * LDK + kc) =
          *(const uint4*)(A + (size_t)(m0 + row) * K + kt * 64 + kc);
      *(uint4*)(Bs + row * LDK + kc) =
          *(const uint4*)(Bt + (size_t)(n0 + row) * K + kt * 64 + kc);
    }
    __syncthreads();
#pragma unroll
    for (int kk = 0; kk < 64; kk += 32) {
      f16x8 af[4], bfr[4];
#pragma unroll
      for (int mi = 0; mi < 4; ++mi)
        af[mi] = *(const f16x8*)(As + (wm + mi * 16 + sl) * LDK + kk + quad * 8);
#pragma unroll
      for (int ni = 0; ni < 4; ++ni)
        bfr[ni] = *(const f16x8*)(Bs + (wn + ni * 16 + sl) * LDK + kk + quad * 8);
#pragma unroll
      for (int mi = 0; mi < 4; ++mi)
#pragma unroll
        for (int ni = 0; ni < 4; ++ni)
          acc[mi][ni] = __builtin_amdgcn_mfma_f32_16x16x32_f16(
              af[mi], bfr[ni], acc[mi][ni], 0, 0, 0);
    }
  }
  // epilogue: D row = quad*4 + reg, col = sl (verified m89/m91 mapping)
#pragma unroll
  for (int mi = 0; mi < 4; ++mi)
#pragma unroll
    for (int ni = 0; ni < 4; ++ni) {
      int row = m0 + wm + mi * 16 + quad * 4;
      int col = n0 + wn + ni * 16 + sl;
#pragma unroll
      for (int r = 0; r < 4; ++r) {
        if (F32OUT)
          ((float*)Cout)[(size_t)(row + r) * N + col] = acc[mi][ni][r];
        else
          ((f16*)Cout)[(size_t)(row + r) * N + col] = (f16)acc[mi][ni][r];
      }
    }
}

// ---------------- sparse attention ----------------
// QKV: f16 [B*S][3*1024], cols: Q=h*64, K=1024+h*64, V=2048+h*64.
// Wave per query row; allowed cols = window [ws..i] plus globals {64t < ws}.
// Phase A: scores via 16-lane-split dots (4 cols in flight per wave).
// Phase B: softmax (max + exp + sum) with 160-entry LDS buffer per wave.
// Phase C: dim-parallel PV, coalesced V loads.
__global__ __launch_bounds__(256) void k_attn(const f16* __restrict__ qkv,
                                              f16* __restrict__ y) {
  __shared__ float sbuf[4][160];
  const int t = threadIdx.x;
  const int wv = t >> 6, l = t & 63, sl = l & 15, quad = l >> 4;
  const int W = blockIdx.x * 4 + wv;  // 4096 waves
  const int chunk = W & 127;          // 128 chunks of 16 rows
  const int bh = W >> 7;              // 0..31
  const int b = bh >> 4, h = bh & 15;
  const f16* base = qkv + (size_t)b * 2048 * 3072;
  const int qc = h * 64, kc = 1024 + h * 64, vc = 2048 + h * 64;
  for (int r = 0; r < 16; ++r) {
    const int i = chunk * 16 + r;
    int ws = i - 127;
    if (ws < 0) ws = 0;
    const int nglob = (ws + 63) >> 6;     // globals strictly below window
    const int T = (i - ws + 1) + nglob;   // <= 158
    const f16x4 q4 = *(const f16x4*)(base + (size_t)i * 3072 + qc + sl * 4);
    const float q0 = (float)q4.x * 0.125f, q1 = (float)q4.y * 0.125f,
                q2 = (float)q4.z * 0.125f, q3 = (float)q4.w * 0.125f;
    float m = -1e30f;
    for (int t0 = 0; t0 < T; t0 += 4) {
      const int tt = t0 + quad;
      const int tc = tt < T ? tt : T - 1;
      const int j = tc < nglob ? tc * 64 : ws + tc - nglob;
      const f16x4 k4 = *(const f16x4*)(base + (size_t)j * 3072 + kc + sl * 4);
      float p = q0 * (float)k4.x + q1 * (float)k4.y + q2 * (float)k4.z +
                q3 * (float)k4.w;
      p += __shfl_xor(p, 1, 16);
      p += __shfl_xor(p, 2, 16);
      p += __shfl_xor(p, 4, 16);
      p += __shfl_xor(p, 8, 16);
      if (tt < T) {
        if (sl == 0) sbuf[wv][tt] = p;
        m = fmaxf(m, p);
      }
    }
    m = fmaxf(m, __shfl_xor(m, 16, 64));
    m = fmaxf(m, __shfl_xor(m, 32, 64));
    float lsum = 0.f;
    for (int tt = l; tt < T; tt += 64) {
      float p = __expf(sbuf[wv][tt] - m);
      sbuf[wv][tt] = p;
      lsum += p;
    }
#pragma unroll
    for (int off = 1; off < 64; off <<= 1) lsum += __shfl_xor(lsum, off, 64);
    // Phase C: o[d=l] = sum_t p_t * V[j_t][d], 4 split accumulators
    float o0 = 0.f, o1 = 0.f, o2 = 0.f, o3 = 0.f;
    int tt = 0;
    for (; tt + 4 <= T; tt += 4) {
      int j0 = tt + 0 < nglob ? (tt + 0) * 64 : ws + tt + 0 - nglob;
      int j1 = tt + 1 < nglob ? (tt + 1) * 64 : ws + tt + 1 - nglob;
      int j2 = tt + 2 < nglob ? (tt + 2) * 64 : ws + tt + 2 - nglob;
      int j3 = tt + 3 < nglob ? (tt + 3) * 64 : ws + tt + 3 - nglob;
      o0 += sbuf[wv][tt + 0] * (float)base[(size_t)j0 * 3072 + vc + l];
      o1 += sbuf[wv][tt + 1] * (float)base[(size_t)j1 * 3072 + vc + l];
      o2 += sbuf[wv][tt + 2] * (float)base[(size_t)j2 * 3072 + vc + l];
      o3 += sbuf[wv][tt + 3] * (float)base[(size_t)j3 * 3072 + vc + l];
    }
    for (; tt < T; ++tt) {
      int j = tt < nglob ? tt * 64 : ws + tt - nglob;
      o0 += sbuf[wv][tt] * (float)base[(size_t)j * 3072 + vc + l];
    }
    const float o = (o0 + o1) + (o2 + o3);
    y[((size_t)b * 2048 + i) * 1024 + h * 64 + l] = (f16)(o / lsum);
  }
}

extern "C" void kernel_launch(void* const* d_in, const int* in_sizes, int n_in,
                              void* d_out, int out_size, void* d_ws,
                              size_t ws_size, hipStream_t stream) {
  (void)in_sizes; (void)n_in; (void)out_size; (void)ws_size;
  const float* x = (const float*)d_in[0];      // [2,2048,1024]
  const float* Wqkv = (const float*)d_in[1];   // [1024,3072]
  const float* Wproj = (const float*)d_in[2];  // [1024,1024]
  float* out = (float*)d_out;                  // [2,2048,1024] fp32
  char* ws = (char*)d_ws;
  // workspace layout (48 MB total)
  f16* Xh     = (f16*)(ws);                         // 4096x1024  (8 MB)
  f16* WqkvT  = (f16*)(ws + (size_t)8  * 1048576);  // 3072x1024  (6 MB)
  f16* WprojT = (f16*)(ws + (size_t)14 * 1048576);  // 1024x1024  (2 MB)
  f16* QKV    = (f16*)(ws + (size_t)16 * 1048576);  // 4096x3072  (24 MB)
  f16* Yh     = (f16*)(ws + (size_t)40 * 1048576);  // 4096x1024  (8 MB)

  k_cvt<<<4096, 256, 0, stream>>>(x, Xh, 4096 * 1024 / 4);
  k_transpose<<<dim3(48, 16), 256, 0, stream>>>(Wqkv, WqkvT, 1024, 3072);
  k_transpose<<<dim3(16, 16), 256, 0, stream>>>(Wproj, WprojT, 1024, 1024);
  k_gemm_bt<0><<<dim3(32, 24), 256, 0, stream>>>(Xh, WqkvT, (void*)QKV, 4096,
                                                 3072, 1024);
  k_attn<<<1024, 256, 0, stream>>>(QKV, Yh);
  k_gemm_bt<1><<<dim3(32, 8), 256, 0, stream>>>(Yh, WprojT, (void*)out, 4096,
                                                1024, 1024);
}

// Round 3
// 175.592 us; speedup vs baseline: 3.9561x; 3.9561x over previous
//
#include <hip/hip_runtime.h>
#include <cstdint>
#include <cstddef>

typedef _Float16 f16;
typedef f16 f16x2 __attribute__((ext_vector_type(2)));
typedef f16 f16x4 __attribute__((ext_vector_type(4)));
typedef f16 f16x8 __attribute__((ext_vector_type(8)));
typedef float f32x4 __attribute__((ext_vector_type(4)));

// ---------------- f32 -> f16 convert (4 elems/thread) ----------------
__global__ __launch_bounds__(256) void k_cvt(const float* __restrict__ in,
                                             f16* __restrict__ out, int n4) {
  int idx = blockIdx.x * 256 + threadIdx.x;
  if (idx < n4) {
    float4 v = ((const float4*)in)[idx];
    f16x4 o;
    o.x = (f16)v.x; o.y = (f16)v.y; o.z = (f16)v.z; o.w = (f16)v.w;
    ((f16x4*)out)[idx] = o;
  }
}

// ------------- transpose f32[K][N] -> f16[N][K], 64x64 tiles -------------
__global__ __launch_bounds__(256) void k_transpose(const float* __restrict__ in,
                                                   f16* __restrict__ out,
                                                   int K, int N) {
  __shared__ float tile[64][65];
  const int t = threadIdx.x, x = t & 63, y0 = t >> 6;
  const int bx = blockIdx.x, by = blockIdx.y;
#pragma unroll
  for (int r = 0; r < 16; ++r) {
    int y = y0 + r * 4;
    tile[y][x] = in[(size_t)(by * 64 + y) * N + bx * 64 + x];
  }
  __syncthreads();
#pragma unroll
  for (int r = 0; r < 16; ++r) {
    int y = y0 + r * 4;
    out[(size_t)(bx * 64 + y) * K + by * 64 + x] = (f16)tile[x][y];
  }
}

// ------------- GEMM: C[M][N] = A[M][K] * Bt[N][K]^T  (f16 in, fp32 acc) ----
template <int F32OUT>
__global__ __launch_bounds__(256) void k_gemm_bt(const f16* __restrict__ A,
                                                 const f16* __restrict__ Bt,
                                                 void* __restrict__ Cout,
                                                 int M, int N, int K) {
  constexpr int LDK = 72;
  __shared__ __align__(16) f16 As[128 * LDK];
  __shared__ __align__(16) f16 Bs[128 * LDK];
  const int t = threadIdx.x;
  const int m0 = blockIdx.x * 128, n0 = blockIdx.y * 128;
  const int w = t >> 6, l = t & 63, sl = l & 15, quad = l >> 4;
  const int wm = (w & 1) * 64, wn = (w >> 1) * 64;
  f32x4 acc[4][4] = {};
  const int nk = K >> 6;
  for (int kt = 0; kt < nk; ++kt) {
    __syncthreads();
#pragma unroll
    for (int c = 0; c < 4; ++c) {
      int cid = t + c * 256;
      int row = cid >> 3;
      int kc = (cid & 7) * 8;
      *(uint4*)(As + row * LDK + kc) =
          *(const uint4*)(A + (size_t)(m0 + row) * K + kt * 64 + kc);
      *(uint4*)(Bs + row * LDK + kc) =
          *(const uint4*)(Bt + (size_t)(n0 + row) * K + kt * 64 + kc);
    }
    __syncthreads();
#pragma unroll
    for (int kk = 0; kk < 64; kk += 32) {
      f16x8 af[4], bfr[4];
#pragma unroll
      for (int mi = 0; mi < 4; ++mi)
        af[mi] = *(const f16x8*)(As + (wm + mi * 16 + sl) * LDK + kk + quad * 8);
#pragma unroll
      for (int ni = 0; ni < 4; ++ni)
        bfr[ni] = *(const f16x8*)(Bs + (wn + ni * 16 + sl) * LDK + kk + quad * 8);
#pragma unroll
      for (int mi = 0; mi < 4; ++mi)
#pragma unroll
        for (int ni = 0; ni < 4; ++ni)
          acc[mi][ni] = __builtin_amdgcn_mfma_f32_16x16x32_f16(
              af[mi], bfr[ni], acc[mi][ni], 0, 0, 0);
    }
  }
#pragma unroll
  for (int mi = 0; mi < 4; ++mi)
#pragma unroll
    for (int ni = 0; ni < 4; ++ni) {
      int row = m0 + wm + mi * 16 + quad * 4;
      int col = n0 + wn + ni * 16 + sl;
#pragma unroll
      for (int r = 0; r < 4; ++r) {
        if (F32OUT)
          ((float*)Cout)[(size_t)(row + r) * N + col] = acc[mi][ni][r];
        else
          ((f16*)Cout)[(size_t)(row + r) * N + col] = (f16)acc[mi][ni][r];
      }
    }
}

// ---------------- MFMA sparse flash attention ----------------
// Block = (b, h, 64-query span). Wave = 16-query tile. Gathered col list for
// the block: ng globals (j=64t < lo) then window union [lo, hi]; per-lane
// computable. QK^T + PV via mfma_f32_16x16x32_f16; V staged transposed in LDS.
__global__ __launch_bounds__(256) void k_attn(const f16* __restrict__ qkv,
                                              f16* __restrict__ y) {
  constexpr int VT = 226;  // Vt row pitch (f16): 113 dwords, odd -> cf writes
  constexpr int PT = 232;  // P row pitch (f16): 464 B, 16B-aligned rows
  __shared__ __align__(16) f16 Vt[64 * VT];    // 28928 B (shared by block)
  __shared__ __align__(16) f16 P[4][16 * PT];  // 29696 B (per wave)
  __shared__ float rmax[4][16];
  __shared__ float lsum[4][16];

  const int t = threadIdx.x, wv = t >> 6, l = t & 63;
  const int sl = l & 15, quad = l >> 4;
  const int blk = blockIdx.x;  // 1024
  const int qb = blk & 31;     // 64-query span
  const int bh = blk >> 5;
  const int b = bh >> 4, h = bh & 15;
  const f16* base = qkv + (size_t)b * 2048 * 3072;
  const int qc = h * 64, kc = 1024 + h * 64, vc = 2048 + h * 64;

  const int row0 = qb * 64;
  const int hi = row0 + 63;
  int lo = row0 - 127; if (lo < 0) lo = 0;
  const int ng = (lo + 63) >> 6;           // globals strictly below lo
  const int T = ng + (hi - lo + 1);        // true col count (<=221)
  int NT = (T + 15) >> 4;
  NT = (NT + 1) & ~1;                      // even # of 16-col tiles (<=14)
  const int NC = NT * 16;                  // padded cols (multiple of 32)

  // ---- phase 1: stage gathered V rows transposed: Vt[d][t] ----
  for (int it = 0; it < NC / 8; ++it) {
    int idx = it * 8 + wv * 2 + (l >> 5);
    int j = idx < ng ? idx * 64 : lo + idx - ng;
    if (idx >= T) j = lo;  // pad: valid addr, killed by p=0
    int d0 = (l & 31) * 2;
    f16x2 v2 = *(const f16x2*)(base + (size_t)j * 3072 + vc + d0);
    Vt[(d0 + 0) * VT + idx] = v2.x;
    Vt[(d0 + 1) * VT + idx] = v2.y;
  }

  // ---- phase 2a: QK^T tiles, mask, raw f16 scores -> P, row max ----
  const int i0 = row0 + wv * 16;
  f16x8 aq[2];
#pragma unroll
  for (int c = 0; c < 2; ++c) {
    f16x8 qv = *(const f16x8*)(base + (size_t)(i0 + sl) * 3072 + qc + c * 32 +
                               quad * 8);
#pragma unroll
    for (int jj = 0; jj < 8; ++jj) qv[jj] = qv[jj] * (f16)0.125f;  // scale
    aq[c] = qv;
  }
  float mloc[4] = {-INFINITY, -INFINITY, -INFINITY, -INFINITY};
  for (int kt = 0; kt < NT; ++kt) {
    const int idx = kt * 16 + sl;
    const bool pad = idx >= T;
    int j = idx < ng ? idx * 64 : lo + idx - ng;
    if (pad) j = lo;
    const f16* kr = base + (size_t)j * 3072 + kc;
    f16x8 bk0 = *(const f16x8*)(kr + quad * 8);
    f16x8 bk1 = *(const f16x8*)(kr + 32 + quad * 8);
    f32x4 s = {0.f, 0.f, 0.f, 0.f};
    s = __builtin_amdgcn_mfma_f32_16x16x32_f16(aq[0], bk0, s, 0, 0, 0);
    s = __builtin_amdgcn_mfma_f32_16x16x32_f16(aq[1], bk1, s, 0, 0, 0);
#pragma unroll
    for (int r = 0; r < 4; ++r) {
      const int i = i0 + quad * 4 + r;
      const bool ok = !pad && (j <= i) && ((i - j) < 128 || (j & 63) == 0);
      const float sv = ok ? s[r] : -INFINITY;
      mloc[r] = fmaxf(mloc[r], sv);
      P[wv][(quad * 4 + r) * PT + idx] = (f16)sv;
    }
  }
#pragma unroll
  for (int off = 1; off < 16; off <<= 1)
#pragma unroll
    for (int r = 0; r < 4; ++r)
      mloc[r] = fmaxf(mloc[r], __shfl_xor(mloc[r], off, 64));
  if (sl == 0)
#pragma unroll
    for (int r = 0; r < 4; ++r) rmax[wv][quad * 4 + r] = mloc[r];
  __syncthreads();  // Vt + P + rmax visible

  // ---- phase 2b: PV with exp(P - m) as A-frags, Vt as B-frags ----
  const int NKC = NC / 32;
  f32x4 o[4] = {};
  float ls = 0.f;
  const float mrow = rmax[wv][sl];  // this lane's A-frag row = sl
  for (int kcc = 0; kcc < NKC; ++kcc) {
    f16x8 raw = *(const f16x8*)(&P[wv][sl * PT + kcc * 32 + quad * 8]);
    f16x8 ap;
#pragma unroll
    for (int jj = 0; jj < 8; ++jj) {
      float p = __expf((float)raw[jj] - mrow);
      ls += p;
      ap[jj] = (f16)p;
    }
#pragma unroll
    for (int dt = 0; dt < 4; ++dt) {
      const uint32_t* vb =
          (const uint32_t*)(Vt + (dt * 16 + sl) * VT + kcc * 32 + quad * 8);
      union { uint32_t u[4]; f16x8 v; } cv;
      cv.u[0] = vb[0]; cv.u[1] = vb[1]; cv.u[2] = vb[2]; cv.u[3] = vb[3];
      o[dt] = __builtin_amdgcn_mfma_f32_16x16x32_f16(ap, cv.v, o[dt], 0, 0, 0);
    }
  }
  ls += __shfl_xor(ls, 16, 64);
  ls += __shfl_xor(ls, 32, 64);
  if (quad == 0) lsum[wv][sl] = ls;
  __syncthreads();
#pragma unroll
  for (int r = 0; r < 4; ++r) {
    const int q = quad * 4 + r;
    const float inv = 1.0f / lsum[wv][q];
    f16* yr = y + ((size_t)b * 2048 + i0 + q) * 1024 + h * 64;
#pragma unroll
    for (int dt = 0; dt < 4; ++dt) yr[dt * 16 + sl] = (f16)(o[dt][r] * inv);
  }
}

extern "C" void kernel_launch(void* const* d_in, const int* in_sizes, int n_in,
                              void* d_out, int out_size, void* d_ws,
                              size_t ws_size, hipStream_t stream) {
  (void)in_sizes; (void)n_in; (void)out_size; (void)ws_size;
  const float* x = (const float*)d_in[0];
  const float* Wqkv = (const float*)d_in[1];
  const float* Wproj = (const float*)d_in[2];
  float* out = (float*)d_out;
  char* ws = (char*)d_ws;
  f16* Xh     = (f16*)(ws);                         // 4096x1024
  f16* WqkvT  = (f16*)(ws + (size_t)8  * 1048576);  // 3072x1024
  f16* WprojT = (f16*)(ws + (size_t)14 * 1048576);  // 1024x1024
  f16* QKV    = (f16*)(ws + (size_t)16 * 1048576);  // 4096x3072
  f16* Yh     = (f16*)(ws + (size_t)40 * 1048576);  // 4096x1024

  k_cvt<<<4096, 256, 0, stream>>>(x, Xh, 4096 * 1024 / 4);
  k_transpose<<<dim3(48, 16), 256, 0, stream>>>(Wqkv, WqkvT, 1024, 3072);
  k_transpose<<<dim3(16, 16), 256, 0, stream>>>(Wproj, WprojT, 1024, 1024);
  k_gemm_bt<0><<<dim3(32, 24), 256, 0, stream>>>(Xh, WqkvT, (void*)QKV, 4096,
                                                 3072, 1024);
  k_attn<<<1024, 256, 0, stream>>>(QKV, Yh);
  k_gemm_bt<1><<<dim3(32, 8), 256, 0, stream>>>(Yh, WprojT, (void*)out, 4096,
                                                1024, 1024);
}